// Round 9
// baseline (369.804 us; speedup 1.0000x reference)
//
#include <hip/hip_runtime.h>

#define EPS 1e-5f

constexpr int NB   = 8;
constexpr int NN   = 2048;
constexpr int DIM  = 128;
constexpr int KNN  = 16;
constexpr int AH   = 512;
constexpr int NPTS = NB * NN;
constexpr float SCALE = 0.08838834764831845f; // 1/sqrt(128)

typedef __attribute__((ext_vector_type(8))) short short8;
typedef __attribute__((ext_vector_type(4))) float floatx4;

// round-half-up bf16 conversion: 2 VALU ops.
__device__ __forceinline__ short f2bf(float f) {
  union { float f; unsigned u; } a; a.f = f;
  return (short)((a.u + 0x8000u) >> 16);
}
__device__ __forceinline__ float bf2f(short s) {
  union { unsigned u; float f; } a; a.u = ((unsigned)(unsigned short)s) << 16;
  return a.f;
}

// ---------------------------------------------------------------------------
// Pack weights into bf16 B-fragment layouts (frag f at [f*512 + lane*8 + j],
// value = W[k = ks*32 + q*8 + j][n]) + folded BN + biases + pos SoA transpose.
// Wf = w_in @ w_qkv computed inline (128-FMA dot, L2-resident weights).
// ---------------------------------------------------------------------------
__global__ __launch_bounds__(256) void pack_weights(
    const float* __restrict__ attn_w1, const float* __restrict__ attn_w2,
    const float* __restrict__ pos_w2, const float* __restrict__ w_in,
    const float* __restrict__ w_qkv,
    const float* __restrict__ w_out, const float* __restrict__ pos,
    const float* __restrict__ attn_b1, const float* __restrict__ abn_g,
    const float* __restrict__ abn_b, const float* __restrict__ abn_m,
    const float* __restrict__ abn_v,
    const float* __restrict__ pos_b1, const float* __restrict__ pbn_g,
    const float* __restrict__ pbn_b, const float* __restrict__ pbn_m,
    const float* __restrict__ pbn_v, const float* __restrict__ pos_b2,
    short* __restrict__ w1p, short* __restrict__ w2p, short* __restrict__ pw2p,
    short* __restrict__ wfp, short* __restrict__ wop,
    float* __restrict__ biasq,
    float* __restrict__ t1sc, float* __restrict__ t1bi,
    float* __restrict__ phsc, float* __restrict__ phbi,
    float* __restrict__ pos_t)
{
  int t = blockIdx.x * 256 + threadIdx.x;
  if (t < 65536) {                       // w1p: [128x512], 8 chunks of 64 cols
    int j = t & 7, lane = (t >> 3) & 63, ks = (t >> 9) & 3, nt = (t >> 11) & 3, ch = t >> 13;
    int q = lane >> 4, cc = lane & 15;
    int k = ks * 32 + q * 8 + j, n = ch * 64 + nt * 16 + cc;
    w1p[t] = f2bf(attn_w1[(size_t)k * AH + n]);
  } else if (t < 131072) {               // w2p: [512x128], 8 chunks of 64 rows
    int e = t - 65536;
    int j = e & 7, lane = (e >> 3) & 63, ks = (e >> 9) & 1, nt = (e >> 10) & 7, ch = e >> 13;
    int q = lane >> 4, cc = lane & 15;
    int k = ch * 64 + ks * 32 + q * 8 + j, n = nt * 16 + cc;
    w2p[e] = f2bf(attn_w2[(size_t)k * DIM + n]);
  } else if (t < 139264) {               // pw2p: pos_w2 [64x128]
    int e = t - 131072;
    int j = e & 7, lane = (e >> 3) & 63, ks = (e >> 9) & 1, nt = e >> 10;
    int q = lane >> 4, cc = lane & 15;
    int k = ks * 32 + q * 8 + j, n = nt * 16 + cc;
    pw2p[e] = f2bf(pos_w2[(size_t)k * DIM + n]);
  } else if (t < 188416) {               // wfp: Wf=w_in@w_qkv [128x384], inline dot
    int e = t - 139264;
    int j = e & 7, lane = (e >> 3) & 63, ks = (e >> 9) & 3, nt = (e >> 11) & 7, nc = e >> 14;
    int q = lane >> 4, cc = lane & 15;
    int k = ks * 32 + q * 8 + j, n = nc * 128 + nt * 16 + cc;
    float s = 0.0f;
#pragma unroll 8
    for (int m = 0; m < 128; ++m)
      s += w_in[(size_t)k * DIM + m] * w_qkv[(size_t)m * 384 + n];
    wfp[e] = f2bf(s);
  } else if (t < 204800) {               // wop: w_out [128x128]
    int e = t - 188416;
    int j = e & 7, lane = (e >> 3) & 63, ks = (e >> 9) & 3, nt = (e >> 11) & 7;
    int q = lane >> 4, cc = lane & 15;
    int k = ks * 32 + q * 8 + j, n = nt * 16 + cc;
    wop[e] = f2bf(w_out[(size_t)k * DIM + n]);
  } else if (t < 205184) {               // biasq[384]: pos_b2 into q,v cols
    int c = t - 204800;
    biasq[c] = (c < 128) ? pos_b2[c] : ((c < 256) ? 0.0f : pos_b2[c - 256]);
  } else if (t < 205696) {
    int c = t - 205184;
    t1sc[c] = abn_g[c] * rsqrtf(abn_v[c] + EPS);
  } else if (t < 206208) {
    int c = t - 205696;
    float sc = abn_g[c] * rsqrtf(abn_v[c] + EPS);
    t1bi[c] = (attn_b1[c] - abn_m[c]) * sc + abn_b[c];
  } else if (t < 206272) {
    int c = t - 206208;
    phsc[c] = pbn_g[c] * rsqrtf(pbn_v[c] + EPS);
  } else if (t < 206336) {
    int c = t - 206272;
    float sc = pbn_g[c] * rsqrtf(pbn_v[c] + EPS);
    phbi[c] = (pos_b1[c] - pbn_m[c]) * sc + pbn_b[c];
  } else if (t < 206336 + NPTS * 3) {    // pos -> SoA pos_t[b][3][NN]
    int e = t - 206336;
    int p = e / 3, d = e - p * 3;
    int b = p >> 11, n = p & (NN - 1);
    pos_t[((size_t)b * 3 + d) * NN + n] = pos[e];
  }
}

// ---------------------------------------------------------------------------
// MFMA GEMM: qkv[16384x384] (bf16 out) = bf16(ori_x) @ wfp + biasq.
// M=64 blocks; 3 col-chunks looped inside (A staged once).
// ---------------------------------------------------------------------------
__global__ __launch_bounds__(256, 4) void gemm_in(
    const float* __restrict__ A, const short* __restrict__ wfp,
    const float* __restrict__ biasq, short* __restrict__ C)
{
  __shared__ short As[64 * 128];
  const int tid = threadIdx.x;
  const int lane = tid & 63, w = tid >> 6;
  const int wr = w >> 1, wc = w & 1;
  const int q = lane >> 4, cc = lane & 15;
  const int row0 = blockIdx.x * 64;
#pragma unroll
  for (int it = 0; it < 4; ++it) {
    int e = tid + it * 256;
    int row = e >> 4, cg = e & 15;
    const float* src = A + (size_t)(row0 + row) * 128 + cg * 8;
    float4 f0 = *(const float4*)src, f1 = *(const float4*)(src + 4);
    short8 v;
    v[0] = f2bf(f0.x); v[1] = f2bf(f0.y); v[2] = f2bf(f0.z); v[3] = f2bf(f0.w);
    v[4] = f2bf(f1.x); v[5] = f2bf(f1.y); v[6] = f2bf(f1.z); v[7] = f2bf(f1.w);
    *(short8*)(As + row * 128 + ((cg ^ (row & 15)) << 3)) = v;
  }
  __syncthreads();
  for (int nc = 0; nc < 3; ++nc) {
    floatx4 acc[2][4];
#pragma unroll
    for (int i = 0; i < 2; ++i)
#pragma unroll
      for (int jt = 0; jt < 4; ++jt) acc[i][jt] = (floatx4){0.f, 0.f, 0.f, 0.f};
#pragma unroll
    for (int ks = 0; ks < 4; ++ks) {
      short8 a8[2], b8[4];
#pragma unroll
      for (int i = 0; i < 2; ++i) {
        int row = (wr * 2 + i) * 16 + cc;
        a8[i] = *(const short8*)(As + row * 128 + (((ks * 4 + q) ^ cc) << 3));
      }
#pragma unroll
      for (int jt = 0; jt < 4; ++jt)
        b8[jt] = *(const short8*)(wfp + ((((nc * 8 + wc * 4 + jt) * 4 + ks) * 64 + lane) << 3));
#pragma unroll
      for (int i = 0; i < 2; ++i)
#pragma unroll
        for (int jt = 0; jt < 4; ++jt)
          acc[i][jt] = __builtin_amdgcn_mfma_f32_16x16x32_bf16(a8[i], b8[jt], acc[i][jt], 0, 0, 0);
    }
#pragma unroll
    for (int jt = 0; jt < 4; ++jt) {
      int colG = nc * 128 + (wc * 4 + jt) * 16 + cc;
      float bv = biasq[colG];
#pragma unroll
      for (int i = 0; i < 2; ++i)
#pragma unroll
        for (int r = 0; r < 4; ++r) {
          int row = (wr * 2 + i) * 16 + q * 4 + r;
          C[(size_t)(row0 + row) * 384 + colG] = f2bf(acc[i][jt][r] + bv);
        }
    }
  }
}

// ---------------------------------------------------------------------------
// Mega-fused: per-wave KNN + pos-MLP + attention MLP + softmax + out-proj.
// 4 points/block (M=64), 4 waves each 32x64, 64-col AH chunks, dbuf t1,
// vpe in LDS (no long live ranges). Epilogue: agg -> LDS -> 16x128x128 MFMA
// out-projection with fp32 residual, written straight to d_out.
// LDS ~50 KB -> 3 blocks/CU. XCD-affinity: batch = blockIdx.x & 7.
// ---------------------------------------------------------------------------
__global__ __launch_bounds__(256, 3) void fused_attn(
    const float* __restrict__ pos_t, const short* __restrict__ qkv,
    const float* __restrict__ pos_w1,
    const short* __restrict__ w1p, const short* __restrict__ w2p,
    const short* __restrict__ pw2p, const short* __restrict__ wop,
    const float* __restrict__ t1sc, const float* __restrict__ t1bi,
    const float* __restrict__ phsc, const float* __restrict__ phbi,
    const float* __restrict__ attn_b2,
    const float* __restrict__ ori_x, float* __restrict__ out)
{
  __shared__ short a_s[64 * 128];       // 16 KB, XOR swizzle on row&15
  __shared__ short vpe_s[64 * 128];     // 16 KB, same swizzle
  __shared__ short t1_s[2][64 * 64];    // 16 KB, XOR swizzle on row&7
  __shared__ short q_ss[4 * 128];       // 1 KB bf16 q rows
  __shared__ float relp_s[64 * 4];
  __shared__ int   nbr_s[64];

  const int tid = threadIdx.x;
  const int lane = tid & 63, w = tid >> 6;
  const int wr = w >> 1, wc = w & 1;
  const int q = lane >> 4, cc = lane & 15;
  const int bb = blockIdx.x & 7;                     // XCD-affinity swizzle
  const int base = (blockIdx.x >> 3) * 4;            // local n of first point
  const int gp0 = bb * NN + base;

  const float* px = pos_t + (size_t)bb * 3 * NN;
  const float* py = px + NN;
  const float* pz = py + NN;

  // --- inline KNN: wave w computes point (base+w)'s 16 nearest ---
  {
    const int il = base + w;
    const float xi = px[il], yi = py[il], zi = pz[il];
    const float sqi = xi * xi + yi * yi + zi * zi;
    float v[32];
#pragma unroll
    for (int t = 0; t < 32; ++t) {
      int j = t * 64 + lane;
      float xj = px[j], yj = py[j], zj = pz[j];
      float sqj = xj * xj + yj * yj + zj * zj;
      float dot = xi * xj + yi * yj + zi * zj;
      v[t] = sqi + sqj - 2.0f * dot;
    }
    for (int s = 0; s < KNN; ++s) {
      float bv = 3.4e38f; int bj = 1 << 30;
#pragma unroll
      for (int t = 0; t < 32; ++t) {
        if (v[t] < bv) { bv = v[t]; bj = t * 64 + lane; }
      }
#pragma unroll
      for (int m = 1; m < 64; m <<= 1) {
        float ov = __shfl_xor(bv, m);
        int   oj = __shfl_xor(bj, m);
        if (ov < bv || (ov == bv && oj < bj)) { bv = ov; bj = oj; }
      }
      if (lane == 0) nbr_s[w * KNN + s] = bj;
#pragma unroll
      for (int t = 0; t < 32; ++t)
        if (bj == t * 64 + lane) v[t] = 3.4e38f;
    }
  }
  __syncthreads();

  if (tid < 64) {                       // relp from SoA pos
    int p = tid >> 4;
    int j = nbr_s[tid];
    relp_s[tid * 4 + 0] = px[base + p] - px[j];
    relp_s[tid * 4 + 1] = py[base + p] - py[j];
    relp_s[tid * 4 + 2] = pz[base + p] - pz[j];
  } else if (tid < 128) {               // stage q rows (bf16)
    int e = tid - 64;
    int p = e >> 4, seg = e & 15;
    *(short8*)(q_ss + p * 128 + seg * 8) =
        *(const short8*)(qkv + (size_t)(gp0 + p) * 384 + seg * 8);
  }
  __syncthreads();

  // ph = relu(bn(relp @ pos_w1 + b1)) -> t1_s[0] (64 rows x 64 cols)
#pragma unroll
  for (int r2 = 0; r2 < 16; ++r2) {
    int e = tid + r2 * 256;
    int row = e >> 6, c = e & 63;
    float lin = relp_s[row * 4] * pos_w1[c] + relp_s[row * 4 + 1] * pos_w1[64 + c]
              + relp_s[row * 4 + 2] * pos_w1[128 + c];
    t1_s[0][row * 64 + (((c >> 3) ^ (row & 7)) << 3) + (c & 7)] =
        f2bf(fmaxf(lin * phsc[c] + phbi[c], 0.0f));
  }
  __syncthreads();

  // pe = ph @ pos_w2 (pos_b2 pre-folded into qkv q/v cols)
  floatx4 pe[2][4];
#pragma unroll
  for (int i = 0; i < 2; ++i)
#pragma unroll
    for (int jt = 0; jt < 4; ++jt) pe[i][jt] = (floatx4){0.f, 0.f, 0.f, 0.f};
#pragma unroll
  for (int ks = 0; ks < 2; ++ks) {
    short8 a8[2];
#pragma unroll
    for (int i = 0; i < 2; ++i) {
      int row = (wr * 2 + i) * 16 + cc;
      a8[i] = *(const short8*)(t1_s[0] + row * 64 + (((ks * 4 + q) ^ (row & 7)) << 3));
    }
#pragma unroll
    for (int jt = 0; jt < 4; ++jt) {
      short8 b8 = *(const short8*)(pw2p + ((((wc * 4 + jt) * 2 + ks) * 64 + lane) << 3));
#pragma unroll
      for (int i = 0; i < 2; ++i)
        pe[i][jt] = __builtin_amdgcn_mfma_f32_16x16x32_bf16(a8[i], b8, pe[i][jt], 0, 0, 0);
    }
  }

  // combine: a = q - k_g + pe -> a_s ; vpe = v_g + pe -> vpe_s
#pragma unroll
  for (int i = 0; i < 2; ++i) {
    int rt = wr * 2 + i;
#pragma unroll
    for (int jt = 0; jt < 4; ++jt) {
      int col = (wc * 4 + jt) * 16 + cc;
      float qv = bf2f(q_ss[rt * 128 + col]);
#pragma unroll
      for (int r = 0; r < 4; ++r) {
        int row = rt * 16 + q * 4 + r;
        const short* kv = qkv + ((size_t)bb * NN + nbr_s[row]) * 384;
        float pev = pe[i][jt][r];
        int slot = row * 128 + (((col >> 3) ^ (row & 15)) << 3) + (col & 7);
        a_s[slot]   = f2bf(qv - bf2f(kv[128 + col]) + pev);
        vpe_s[slot] = f2bf(bf2f(kv[256 + col]) + pev);
      }
    }
  }
  __syncthreads();   // a_s fully built; pe reads of t1_s[0] complete

  floatx4 hacc[2][4];
#pragma unroll
  for (int i = 0; i < 2; ++i)
#pragma unroll
    for (int jt = 0; jt < 4; ++jt) hacc[i][jt] = (floatx4){0.f, 0.f, 0.f, 0.f};

  for (int ch = 0; ch < 8; ++ch) {
    short* t1b = t1_s[ch & 1];
    // GEMM1: tacc = a @ w1[:, ch*64 : +64]
    floatx4 tacc[2][2];
#pragma unroll
    for (int i = 0; i < 2; ++i)
#pragma unroll
      for (int jt = 0; jt < 2; ++jt) tacc[i][jt] = (floatx4){0.f, 0.f, 0.f, 0.f};
#pragma unroll
    for (int ks = 0; ks < 4; ++ks) {
      short8 a8[2], b8[2];
#pragma unroll
      for (int i = 0; i < 2; ++i) {
        int row = (wr * 2 + i) * 16 + cc;
        a8[i] = *(const short8*)(a_s + row * 128 + (((ks * 4 + q) ^ cc) << 3));
      }
#pragma unroll
      for (int jt = 0; jt < 2; ++jt)
        b8[jt] = *(const short8*)(w1p + ((((ch * 4 + wc * 2 + jt) * 4 + ks) * 64 + lane) << 3));
#pragma unroll
      for (int i = 0; i < 2; ++i)
#pragma unroll
        for (int jt = 0; jt < 2; ++jt)
          tacc[i][jt] = __builtin_amdgcn_mfma_f32_16x16x32_bf16(a8[i], b8[jt], tacc[i][jt], 0, 0, 0);
    }
    // bn/relu -> t1b (64-col, swizzled)
#pragma unroll
    for (int jt = 0; jt < 2; ++jt) {
      int colL = (wc * 2 + jt) * 16 + cc;
      int colG = ch * 64 + colL;
      float sc = t1sc[colG], bi = t1bi[colG];
#pragma unroll
      for (int i = 0; i < 2; ++i)
#pragma unroll
        for (int r = 0; r < 4; ++r) {
          int row = (wr * 2 + i) * 16 + q * 4 + r;
          t1b[row * 64 + (((colL >> 3) ^ (row & 7)) << 3) + (colL & 7)] =
              f2bf(fmaxf(tacc[i][jt][r] * sc + bi, 0.0f));
        }
    }
    __syncthreads();   // t1b visible; ping-pong protects in-flight reads
    // GEMM2: hacc += t1 @ w2[ch*64 : +64, :]
#pragma unroll
    for (int ks = 0; ks < 2; ++ks) {
      short8 a8[2], b8[4];
#pragma unroll
      for (int i = 0; i < 2; ++i) {
        int row = (wr * 2 + i) * 16 + cc;
        a8[i] = *(const short8*)(t1b + row * 64 + (((ks * 4 + q) ^ (row & 7)) << 3));
      }
#pragma unroll
      for (int jt = 0; jt < 4; ++jt)
        b8[jt] = *(const short8*)(w2p + ((((ch * 8 + wc * 4 + jt) * 2 + ks) * 64 + lane) << 3));
#pragma unroll
      for (int i = 0; i < 2; ++i)
#pragma unroll
        for (int jt = 0; jt < 4; ++jt)
          hacc[i][jt] = __builtin_amdgcn_mfma_f32_16x16x32_bf16(a8[i], b8[jt], hacc[i][jt], 0, 0, 0);
    }
  }

  // softmax over 16 neighbors per (point, channel); agg -> agg_s (bf16, LDS)
  short* agg_s = t1_s[0];   // 16 rows x 128 cols bf16 (rows 0..3 = points)
#pragma unroll
  for (int r2 = 0; r2 < 6; ++r2) {      // zero pad rows 4..15 (12*128=1536)
    int e = tid + r2 * 256;
    agg_s[(4 + (e >> 7)) * 128 + (e & 127)] = 0;
  }
#pragma unroll
  for (int i = 0; i < 2; ++i) {
    int rt = wr * 2 + i;
#pragma unroll
    for (int jt = 0; jt < 4; ++jt) {
      int col = (wc * 4 + jt) * 16 + cc;
      float b2v = attn_b2[col];
      float v0[4], mx = -3.4e38f;
#pragma unroll
      for (int r = 0; r < 4; ++r) {
        v0[r] = (hacc[i][jt][r] + b2v) * SCALE;
        mx = fmaxf(mx, v0[r]);
      }
      mx = fmaxf(mx, __shfl_xor(mx, 16));
      mx = fmaxf(mx, __shfl_xor(mx, 32));
      float ex[4], sum = 0.f;
#pragma unroll
      for (int r = 0; r < 4; ++r) { ex[r] = __expf(v0[r] - mx); sum += ex[r]; }
      sum += __shfl_xor(sum, 16);
      sum += __shfl_xor(sum, 32);
      float inv = 1.0f / sum;
      float part = 0.f;
#pragma unroll
      for (int r = 0; r < 4; ++r) {
        int row = rt * 16 + q * 4 + r;
        int slot = row * 128 + (((col >> 3) ^ (row & 15)) << 3) + (col & 7);
        part += ex[r] * bf2f(vpe_s[slot]);
      }
      part += __shfl_xor(part, 16);
      part += __shfl_xor(part, 32);
      if (q == 0) agg_s[rt * 128 + col] = f2bf(part * inv);
    }
  }
  __syncthreads();

  // out-projection: out[4x128] = agg @ w_out + ori_x (one 16-row M-tile)
  {
    floatx4 oacc[2];
#pragma unroll
    for (int jt = 0; jt < 2; ++jt) oacc[jt] = (floatx4){0.f, 0.f, 0.f, 0.f};
#pragma unroll
    for (int ks = 0; ks < 4; ++ks) {
      short8 a8 = *(const short8*)(agg_s + cc * 128 + ks * 32 + q * 8);
#pragma unroll
      for (int jt = 0; jt < 2; ++jt) {
        short8 b8 = *(const short8*)(wop + ((((w * 2 + jt) * 4 + ks) * 64 + lane) << 3));
        oacc[jt] = __builtin_amdgcn_mfma_f32_16x16x32_bf16(a8, b8, oacc[jt], 0, 0, 0);
      }
    }
    if (q == 0) {
#pragma unroll
      for (int jt = 0; jt < 2; ++jt) {
        int col = (w * 2 + jt) * 16 + cc;
#pragma unroll
        for (int r = 0; r < 4; ++r) {
          size_t o = (size_t)(gp0 + r) * 128 + col;
          out[o] = oacc[jt][r] + ori_x[o];
        }
      }
    }
  }
}

extern "C" void kernel_launch(void* const* d_in, const int* in_sizes, int n_in,
                              void* d_out, int out_size, void* d_ws, size_t ws_size,
                              hipStream_t stream)
{
  const float* ori_x    = (const float*)d_in[0];
  const float* pos      = (const float*)d_in[1];
  const float* w_in     = (const float*)d_in[2];
  const float* w_qkv    = (const float*)d_in[3];
  const float* w_out    = (const float*)d_in[4];
  const float* pos_w1   = (const float*)d_in[5];
  const float* pos_b1   = (const float*)d_in[6];
  const float* pos_bn_g = (const float*)d_in[7];
  const float* pos_bn_b = (const float*)d_in[8];
  const float* pos_bn_m = (const float*)d_in[9];
  const float* pos_bn_v = (const float*)d_in[10];
  const float* pos_w2   = (const float*)d_in[11];
  const float* pos_b2   = (const float*)d_in[12];
  const float* attn_w1  = (const float*)d_in[13];
  const float* attn_b1  = (const float*)d_in[14];
  const float* attn_bn_g = (const float*)d_in[15];
  const float* attn_bn_b = (const float*)d_in[16];
  const float* attn_bn_m = (const float*)d_in[17];
  const float* attn_bn_v = (const float*)d_in[18];
  const float* attn_w2  = (const float*)d_in[19];
  const float* attn_b2  = (const float*)d_in[20];
  float* out = (float*)d_out;

  short* qkvb = (short*)d_ws;                          // [NPTS*384] bf16
  short* w1p  = qkvb + (size_t)NPTS * 3 * DIM;
  short* w2p  = w1p + 65536;
  short* pw2p = w2p + 65536;
  short* wfp  = pw2p + 8192;
  short* wop  = wfp + 49152;
  float* biasq = (float*)(wop + 16384);
  float* t1sc = biasq + 384;
  float* t1bi = t1sc + 512;
  float* phsc = t1bi + 512;
  float* phbi = phsc + 64;
  float* pos_t = phbi + 64;                            // [NB*3*NN]

  pack_weights<<<998, 256, 0, stream>>>(attn_w1, attn_w2, pos_w2, w_in, w_qkv,
      w_out, pos,
      attn_b1, attn_bn_g, attn_bn_b, attn_bn_m, attn_bn_v,
      pos_b1, pos_bn_g, pos_bn_b, pos_bn_m, pos_bn_v, pos_b2,
      w1p, w2p, pw2p, wfp, wop, biasq, t1sc, t1bi, phsc, phbi, pos_t);
  gemm_in<<<NPTS / 64, 256, 0, stream>>>(ori_x, wfp, biasq, qkvb);
  fused_attn<<<NPTS / 4, 256, 0, stream>>>(pos_t, qkvb, pos_w1,
      w1p, w2p, pw2p, wop, t1sc, t1bi, phsc, phbi, attn_b2, ori_x, out);
}

// Round 10
// 366.067 us; speedup vs baseline: 1.0102x; 1.0102x over previous
//
#include <hip/hip_runtime.h>

#define EPS 1e-5f

constexpr int NB   = 8;
constexpr int NN   = 2048;
constexpr int DIM  = 128;
constexpr int KNN  = 16;
constexpr int AH   = 512;
constexpr int NPTS = NB * NN;
constexpr float SCALE = 0.08838834764831845f; // 1/sqrt(128)

typedef __attribute__((ext_vector_type(8))) short short8;
typedef __attribute__((ext_vector_type(4))) float floatx4;

// round-half-up bf16 conversion: 2 VALU ops.
__device__ __forceinline__ short f2bf(float f) {
  union { float f; unsigned u; } a; a.f = f;
  return (short)((a.u + 0x8000u) >> 16);
}
__device__ __forceinline__ float bf2f(short s) {
  union { unsigned u; float f; } a; a.u = ((unsigned)(unsigned short)s) << 16;
  return a.f;
}

// ---------------------------------------------------------------------------
// Pack weights into bf16 B-fragment layouts (frag f at [f*512 + lane*8 + j],
// value = W[k = ks*32 + q*8 + j][n]) + folded BN + biases + pos SoA transpose.
// Wf = w_in @ w_qkv computed inline.
// ---------------------------------------------------------------------------
__global__ __launch_bounds__(256) void pack_weights(
    const float* __restrict__ attn_w1, const float* __restrict__ attn_w2,
    const float* __restrict__ pos_w2, const float* __restrict__ w_in,
    const float* __restrict__ w_qkv,
    const float* __restrict__ w_out, const float* __restrict__ pos,
    const float* __restrict__ attn_b1, const float* __restrict__ abn_g,
    const float* __restrict__ abn_b, const float* __restrict__ abn_m,
    const float* __restrict__ abn_v,
    const float* __restrict__ pos_b1, const float* __restrict__ pbn_g,
    const float* __restrict__ pbn_b, const float* __restrict__ pbn_m,
    const float* __restrict__ pbn_v, const float* __restrict__ pos_b2,
    short* __restrict__ w1p, short* __restrict__ w2p, short* __restrict__ pw2p,
    short* __restrict__ wfp, short* __restrict__ wop,
    float* __restrict__ biasq,
    float* __restrict__ t1sc, float* __restrict__ t1bi,
    float* __restrict__ phsc, float* __restrict__ phbi,
    float* __restrict__ pos_t)
{
  int t = blockIdx.x * 256 + threadIdx.x;
  if (t < 65536) {                       // w1p: [128x512], 8 chunks of 64 cols
    int j = t & 7, lane = (t >> 3) & 63, ks = (t >> 9) & 3, nt = (t >> 11) & 3, ch = t >> 13;
    int q = lane >> 4, cc = lane & 15;
    int k = ks * 32 + q * 8 + j, n = ch * 64 + nt * 16 + cc;
    w1p[t] = f2bf(attn_w1[(size_t)k * AH + n]);
  } else if (t < 131072) {               // w2p: [512x128], 8 chunks of 64 rows
    int e = t - 65536;
    int j = e & 7, lane = (e >> 3) & 63, ks = (e >> 9) & 1, nt = (e >> 10) & 7, ch = e >> 13;
    int q = lane >> 4, cc = lane & 15;
    int k = ch * 64 + ks * 32 + q * 8 + j, n = nt * 16 + cc;
    w2p[e] = f2bf(attn_w2[(size_t)k * DIM + n]);
  } else if (t < 139264) {               // pw2p: pos_w2 [64x128]
    int e = t - 131072;
    int j = e & 7, lane = (e >> 3) & 63, ks = (e >> 9) & 1, nt = e >> 10;
    int q = lane >> 4, cc = lane & 15;
    int k = ks * 32 + q * 8 + j, n = nt * 16 + cc;
    pw2p[e] = f2bf(pos_w2[(size_t)k * DIM + n]);
  } else if (t < 188416) {               // wfp: Wf=w_in@w_qkv [128x384], inline dot
    int e = t - 139264;
    int j = e & 7, lane = (e >> 3) & 63, ks = (e >> 9) & 3, nt = (e >> 11) & 7, nc = e >> 14;
    int q = lane >> 4, cc = lane & 15;
    int k = ks * 32 + q * 8 + j, n = nc * 128 + nt * 16 + cc;
    float s = 0.0f;
#pragma unroll 8
    for (int m = 0; m < 128; ++m)
      s += w_in[(size_t)k * DIM + m] * w_qkv[(size_t)m * 384 + n];
    wfp[e] = f2bf(s);
  } else if (t < 204800) {               // wop: w_out [128x128]
    int e = t - 188416;
    int j = e & 7, lane = (e >> 3) & 63, ks = (e >> 9) & 3, nt = (e >> 11) & 7;
    int q = lane >> 4, cc = lane & 15;
    int k = ks * 32 + q * 8 + j, n = nt * 16 + cc;
    wop[e] = f2bf(w_out[(size_t)k * DIM + n]);
  } else if (t < 205184) {               // biasq[384]: pos_b2 into q,v cols
    int c = t - 204800;
    biasq[c] = (c < 128) ? pos_b2[c] : ((c < 256) ? 0.0f : pos_b2[c - 256]);
  } else if (t < 205696) {
    int c = t - 205184;
    t1sc[c] = abn_g[c] * rsqrtf(abn_v[c] + EPS);
  } else if (t < 206208) {
    int c = t - 205696;
    float sc = abn_g[c] * rsqrtf(abn_v[c] + EPS);
    t1bi[c] = (attn_b1[c] - abn_m[c]) * sc + abn_b[c];
  } else if (t < 206272) {
    int c = t - 206208;
    phsc[c] = pbn_g[c] * rsqrtf(pbn_v[c] + EPS);
  } else if (t < 206336) {
    int c = t - 206272;
    float sc = pbn_g[c] * rsqrtf(pbn_v[c] + EPS);
    phbi[c] = (pos_b1[c] - pbn_m[c]) * sc + pbn_b[c];
  } else if (t < 206336 + NPTS * 3) {    // pos -> SoA pos_t[b][3][NN]
    int e = t - 206336;
    int p = e / 3, d = e - p * 3;
    int b = p >> 11, n = p & (NN - 1);
    pos_t[((size_t)b * 3 + d) * NN + n] = pos[e];
  }
}

// ---------------------------------------------------------------------------
// Grid-fused: gemm_in (256 tile-blocks) + KNN (4096 point-quad blocks), one
// dispatch. Interleave roles (bx%17==0 -> gemm) so both pipe classes (MFMA/
// LDS vs VALU/shfl) co-schedule on every CU (m114: time ~= max, not sum).
// ---------------------------------------------------------------------------
__global__ __launch_bounds__(256, 4) void knn_gemm_in(
    const float* __restrict__ A, const short* __restrict__ wfp,
    const float* __restrict__ biasq, short* __restrict__ C,
    const float* __restrict__ pos_t, int* __restrict__ idx_out)
{
  __shared__ short As[64 * 128];
  const int tid = threadIdx.x;
  const int bx = blockIdx.x;

  if (bx % 17 == 0) {
    // ---- gemm_in tile: qkv[64x384] = bf16(ori_x tile) @ wfp + biasq ----
    const int lane = tid & 63, w = tid >> 6;
    const int wr = w >> 1, wc = w & 1;
    const int q = lane >> 4, cc = lane & 15;
    const int row0 = (bx / 17) * 64;
#pragma unroll
    for (int it = 0; it < 4; ++it) {
      int e = tid + it * 256;
      int row = e >> 4, cg = e & 15;
      const float* src = A + (size_t)(row0 + row) * 128 + cg * 8;
      float4 f0 = *(const float4*)src, f1 = *(const float4*)(src + 4);
      short8 v;
      v[0] = f2bf(f0.x); v[1] = f2bf(f0.y); v[2] = f2bf(f0.z); v[3] = f2bf(f0.w);
      v[4] = f2bf(f1.x); v[5] = f2bf(f1.y); v[6] = f2bf(f1.z); v[7] = f2bf(f1.w);
      *(short8*)(As + row * 128 + ((cg ^ (row & 15)) << 3)) = v;
    }
    __syncthreads();
    for (int nc = 0; nc < 3; ++nc) {
      floatx4 acc[2][4];
#pragma unroll
      for (int i = 0; i < 2; ++i)
#pragma unroll
        for (int jt = 0; jt < 4; ++jt) acc[i][jt] = (floatx4){0.f, 0.f, 0.f, 0.f};
#pragma unroll
      for (int ks = 0; ks < 4; ++ks) {
        short8 a8[2], b8[4];
#pragma unroll
        for (int i = 0; i < 2; ++i) {
          int row = (wr * 2 + i) * 16 + cc;
          a8[i] = *(const short8*)(As + row * 128 + (((ks * 4 + q) ^ cc) << 3));
        }
#pragma unroll
        for (int jt = 0; jt < 4; ++jt)
          b8[jt] = *(const short8*)(wfp + ((((nc * 8 + wc * 4 + jt) * 4 + ks) * 64 + lane) << 3));
#pragma unroll
        for (int i = 0; i < 2; ++i)
#pragma unroll
          for (int jt = 0; jt < 4; ++jt)
            acc[i][jt] = __builtin_amdgcn_mfma_f32_16x16x32_bf16(a8[i], b8[jt], acc[i][jt], 0, 0, 0);
      }
#pragma unroll
      for (int jt = 0; jt < 4; ++jt) {
        int colG = nc * 128 + (wc * 4 + jt) * 16 + cc;
        float bv = biasq[colG];
#pragma unroll
        for (int i = 0; i < 2; ++i)
#pragma unroll
          for (int r = 0; r < 4; ++r) {
            int row = (wr * 2 + i) * 16 + q * 4 + r;
            C[(size_t)(row0 + row) * 384 + colG] = f2bf(acc[i][jt][r] + bv);
          }
      }
    }
  } else {
    // ---- KNN: 4 points, one wave each; 32 dists/lane; 16 argmin rounds ----
    const int kb = bx - bx / 17 - 1;          // 0..4095
    const int lane = tid & 63;
    const int p = kb * 4 + (tid >> 6);
    const int b = p >> 11, i = p & (NN - 1);
    const float* px = pos_t + (size_t)b * 3 * NN;
    const float* py = px + NN;
    const float* pz = py + NN;
    const float xi = px[i], yi = py[i], zi = pz[i];
    const float sqi = xi * xi + yi * yi + zi * zi;
    float v[32];
#pragma unroll
    for (int t = 0; t < 32; ++t) {
      int j = t * 64 + lane;
      float xj = px[j], yj = py[j], zj = pz[j];
      float sqj = xj * xj + yj * yj + zj * zj;
      float dot = xi * xj + yi * yj + zi * zj;
      v[t] = sqi + sqj - 2.0f * dot;
    }
    for (int s = 0; s < KNN; ++s) {
      float bv = 3.4e38f; int bj = 1 << 30;
#pragma unroll
      for (int t = 0; t < 32; ++t) {
        if (v[t] < bv) { bv = v[t]; bj = t * 64 + lane; }
      }
#pragma unroll
      for (int m = 1; m < 64; m <<= 1) {
        float ov = __shfl_xor(bv, m);
        int   oj = __shfl_xor(bj, m);
        if (ov < bv || (ov == bv && oj < bj)) { bv = ov; bj = oj; }
      }
      if (lane == 0) idx_out[(size_t)p * KNN + s] = bj;
#pragma unroll
      for (int t = 0; t < 32; ++t)
        if (bj == t * 64 + lane) v[t] = 3.4e38f;
    }
  }
}

// ---------------------------------------------------------------------------
// Fused MFMA attention + out-projection: 4 points/block (M=64), 4 waves each
// 32x64, 64-col AH chunks, dbuf t1, vpe in LDS. Epilogue: softmax -> agg in
// LDS -> 16x128x128 MFMA out-proj + fp32 residual -> d_out.
// LDS ~50 KB -> 3 blocks/CU. XCD-affinity: batch = blockIdx.x & 7.
// ---------------------------------------------------------------------------
__global__ __launch_bounds__(256, 3) void fused_attn(
    const float* __restrict__ pos_t, const short* __restrict__ qkv,
    const int* __restrict__ knn_idx,
    const float* __restrict__ pos_w1,
    const short* __restrict__ w1p, const short* __restrict__ w2p,
    const short* __restrict__ pw2p, const short* __restrict__ wop,
    const float* __restrict__ t1sc, const float* __restrict__ t1bi,
    const float* __restrict__ phsc, const float* __restrict__ phbi,
    const float* __restrict__ attn_b2,
    const float* __restrict__ ori_x, float* __restrict__ out)
{
  __shared__ short a_s[64 * 128];       // 16 KB, XOR swizzle on row&15
  __shared__ short vpe_s[64 * 128];     // 16 KB, same swizzle
  __shared__ short t1_s[2][64 * 64];    // 16 KB, XOR swizzle on row&7
  __shared__ short q_ss[4 * 128];       // 1 KB bf16 q rows
  __shared__ float relp_s[64 * 4];
  __shared__ int   nbr_s[64];

  const int tid = threadIdx.x;
  const int lane = tid & 63, w = tid >> 6;
  const int wr = w >> 1, wc = w & 1;
  const int q = lane >> 4, cc = lane & 15;
  const int bb = blockIdx.x & 7;                     // XCD-affinity swizzle
  const int base = (blockIdx.x >> 3) * 4;
  const int gp0 = bb * NN + base;

  const float* px = pos_t + (size_t)bb * 3 * NN;
  const float* py = px + NN;
  const float* pz = py + NN;

  if (tid < 64) nbr_s[tid] = knn_idx[(size_t)gp0 * KNN + tid];
  else if (tid < 128) {                 // stage q rows (bf16)
    int e = tid - 64;
    int p = e >> 4, seg = e & 15;
    *(short8*)(q_ss + p * 128 + seg * 8) =
        *(const short8*)(qkv + (size_t)(gp0 + p) * 384 + seg * 8);
  }
  __syncthreads();
  if (tid < 64) {
    int p = tid >> 4;
    int j = nbr_s[tid];
    relp_s[tid * 4 + 0] = px[base + p] - px[j];
    relp_s[tid * 4 + 1] = py[base + p] - py[j];
    relp_s[tid * 4 + 2] = pz[base + p] - pz[j];
  }
  __syncthreads();

  // ph = relu(bn(relp @ pos_w1 + b1)) -> t1_s[0] (64 rows x 64 cols)
#pragma unroll
  for (int r2 = 0; r2 < 16; ++r2) {
    int e = tid + r2 * 256;
    int row = e >> 6, c = e & 63;
    float lin = relp_s[row * 4] * pos_w1[c] + relp_s[row * 4 + 1] * pos_w1[64 + c]
              + relp_s[row * 4 + 2] * pos_w1[128 + c];
    t1_s[0][row * 64 + (((c >> 3) ^ (row & 7)) << 3) + (c & 7)] =
        f2bf(fmaxf(lin * phsc[c] + phbi[c], 0.0f));
  }
  __syncthreads();

  // pe = ph @ pos_w2 (pos_b2 pre-folded into qkv q/v cols)
  floatx4 pe[2][4];
#pragma unroll
  for (int i = 0; i < 2; ++i)
#pragma unroll
    for (int jt = 0; jt < 4; ++jt) pe[i][jt] = (floatx4){0.f, 0.f, 0.f, 0.f};
#pragma unroll
  for (int ks = 0; ks < 2; ++ks) {
    short8 a8[2];
#pragma unroll
    for (int i = 0; i < 2; ++i) {
      int row = (wr * 2 + i) * 16 + cc;
      a8[i] = *(const short8*)(t1_s[0] + row * 64 + (((ks * 4 + q) ^ (row & 7)) << 3));
    }
#pragma unroll
    for (int jt = 0; jt < 4; ++jt) {
      short8 b8 = *(const short8*)(pw2p + ((((wc * 4 + jt) * 2 + ks) * 64 + lane) << 3));
#pragma unroll
      for (int i = 0; i < 2; ++i)
        pe[i][jt] = __builtin_amdgcn_mfma_f32_16x16x32_bf16(a8[i], b8, pe[i][jt], 0, 0, 0);
    }
  }

  // combine: a = q - k_g + pe -> a_s ; vpe = v_g + pe -> vpe_s
#pragma unroll
  for (int i = 0; i < 2; ++i) {
    int rt = wr * 2 + i;
#pragma unroll
    for (int jt = 0; jt < 4; ++jt) {
      int col = (wc * 4 + jt) * 16 + cc;
      float qv = bf2f(q_ss[rt * 128 + col]);
#pragma unroll
      for (int r = 0; r < 4; ++r) {
        int row = rt * 16 + q * 4 + r;
        const short* kv = qkv + ((size_t)bb * NN + nbr_s[row]) * 384;
        float pev = pe[i][jt][r];
        int slot = row * 128 + (((col >> 3) ^ (row & 15)) << 3) + (col & 7);
        a_s[slot]   = f2bf(qv - bf2f(kv[128 + col]) + pev);
        vpe_s[slot] = f2bf(bf2f(kv[256 + col]) + pev);
      }
    }
  }
  __syncthreads();   // a_s fully built; pe reads of t1_s[0] complete

  floatx4 hacc[2][4];
#pragma unroll
  for (int i = 0; i < 2; ++i)
#pragma unroll
    for (int jt = 0; jt < 4; ++jt) hacc[i][jt] = (floatx4){0.f, 0.f, 0.f, 0.f};

  for (int ch = 0; ch < 8; ++ch) {
    short* t1b = t1_s[ch & 1];
    // GEMM1: tacc = a @ w1[:, ch*64 : +64]
    floatx4 tacc[2][2];
#pragma unroll
    for (int i = 0; i < 2; ++i)
#pragma unroll
      for (int jt = 0; jt < 2; ++jt) tacc[i][jt] = (floatx4){0.f, 0.f, 0.f, 0.f};
#pragma unroll
    for (int ks = 0; ks < 4; ++ks) {
      short8 a8[2], b8[2];
#pragma unroll
      for (int i = 0; i < 2; ++i) {
        int row = (wr * 2 + i) * 16 + cc;
        a8[i] = *(const short8*)(a_s + row * 128 + (((ks * 4 + q) ^ cc) << 3));
      }
#pragma unroll
      for (int jt = 0; jt < 2; ++jt)
        b8[jt] = *(const short8*)(w1p + ((((ch * 4 + wc * 2 + jt) * 4 + ks) * 64 + lane) << 3));
#pragma unroll
      for (int i = 0; i < 2; ++i)
#pragma unroll
        for (int jt = 0; jt < 2; ++jt)
          tacc[i][jt] = __builtin_amdgcn_mfma_f32_16x16x32_bf16(a8[i], b8[jt], tacc[i][jt], 0, 0, 0);
    }
    // bn/relu -> t1b (64-col, swizzled)
#pragma unroll
    for (int jt = 0; jt < 2; ++jt) {
      int colL = (wc * 2 + jt) * 16 + cc;
      int colG = ch * 64 + colL;
      float sc = t1sc[colG], bi = t1bi[colG];
#pragma unroll
      for (int i = 0; i < 2; ++i)
#pragma unroll
        for (int r = 0; r < 4; ++r) {
          int row = (wr * 2 + i) * 16 + q * 4 + r;
          t1b[row * 64 + (((colL >> 3) ^ (row & 7)) << 3) + (colL & 7)] =
              f2bf(fmaxf(tacc[i][jt][r] * sc + bi, 0.0f));
        }
    }
    __syncthreads();   // t1b visible; ping-pong protects in-flight reads
    // GEMM2: hacc += t1 @ w2[ch*64 : +64, :]
#pragma unroll
    for (int ks = 0; ks < 2; ++ks) {
      short8 a8[2], b8[4];
#pragma unroll
      for (int i = 0; i < 2; ++i) {
        int row = (wr * 2 + i) * 16 + cc;
        a8[i] = *(const short8*)(t1b + row * 64 + (((ks * 4 + q) ^ (row & 7)) << 3));
      }
#pragma unroll
      for (int jt = 0; jt < 4; ++jt)
        b8[jt] = *(const short8*)(w2p + ((((ch * 8 + wc * 4 + jt) * 2 + ks) * 64 + lane) << 3));
#pragma unroll
      for (int i = 0; i < 2; ++i)
#pragma unroll
        for (int jt = 0; jt < 4; ++jt)
          hacc[i][jt] = __builtin_amdgcn_mfma_f32_16x16x32_bf16(a8[i], b8[jt], hacc[i][jt], 0, 0, 0);
    }
  }

  // softmax over 16 neighbors per (point, channel); agg -> agg_s (bf16, LDS)
  short* agg_s = t1_s[0];   // 16 rows x 128 cols bf16 (rows 0..3 = points)
#pragma unroll
  for (int r2 = 0; r2 < 6; ++r2) {      // zero pad rows 4..15
    int e = tid + r2 * 256;
    agg_s[(4 + (e >> 7)) * 128 + (e & 127)] = 0;
  }
#pragma unroll
  for (int i = 0; i < 2; ++i) {
    int rt = wr * 2 + i;
#pragma unroll
    for (int jt = 0; jt < 4; ++jt) {
      int col = (wc * 4 + jt) * 16 + cc;
      float b2v = attn_b2[col];
      float v0[4], mx = -3.4e38f;
#pragma unroll
      for (int r = 0; r < 4; ++r) {
        v0[r] = (hacc[i][jt][r] + b2v) * SCALE;
        mx = fmaxf(mx, v0[r]);
      }
      mx = fmaxf(mx, __shfl_xor(mx, 16));
      mx = fmaxf(mx, __shfl_xor(mx, 32));
      float ex[4], sum = 0.f;
#pragma unroll
      for (int r = 0; r < 4; ++r) { ex[r] = __expf(v0[r] - mx); sum += ex[r]; }
      sum += __shfl_xor(sum, 16);
      sum += __shfl_xor(sum, 32);
      float inv = 1.0f / sum;
      float part = 0.f;
#pragma unroll
      for (int r = 0; r < 4; ++r) {
        int row = rt * 16 + q * 4 + r;
        int slot = row * 128 + (((col >> 3) ^ (row & 15)) << 3) + (col & 7);
        part += ex[r] * bf2f(vpe_s[slot]);
      }
      part += __shfl_xor(part, 16);
      part += __shfl_xor(part, 32);
      if (q == 0) agg_s[rt * 128 + col] = f2bf(part * inv);
    }
  }
  __syncthreads();

  // out-projection: out[4x128] = agg @ w_out + ori_x (one 16-row M-tile)
  {
    floatx4 oacc[2];
#pragma unroll
    for (int jt = 0; jt < 2; ++jt) oacc[jt] = (floatx4){0.f, 0.f, 0.f, 0.f};
#pragma unroll
    for (int ks = 0; ks < 4; ++ks) {
      short8 a8 = *(const short8*)(agg_s + cc * 128 + ks * 32 + q * 8);
#pragma unroll
      for (int jt = 0; jt < 2; ++jt) {
        short8 b8 = *(const short8*)(wop + ((((w * 2 + jt) * 4 + ks) * 64 + lane) << 3));
        oacc[jt] = __builtin_amdgcn_mfma_f32_16x16x32_bf16(a8, b8, oacc[jt], 0, 0, 0);
      }
    }
    if (q == 0) {
#pragma unroll
      for (int jt = 0; jt < 2; ++jt) {
        int col = (w * 2 + jt) * 16 + cc;
#pragma unroll
        for (int r = 0; r < 4; ++r) {
          size_t o = (size_t)(gp0 + r) * 128 + col;
          out[o] = oacc[jt][r] + ori_x[o];
        }
      }
    }
  }
}

extern "C" void kernel_launch(void* const* d_in, const int* in_sizes, int n_in,
                              void* d_out, int out_size, void* d_ws, size_t ws_size,
                              hipStream_t stream)
{
  const float* ori_x    = (const float*)d_in[0];
  const float* pos      = (const float*)d_in[1];
  const float* w_in     = (const float*)d_in[2];
  const float* w_qkv    = (const float*)d_in[3];
  const float* w_out    = (const float*)d_in[4];
  const float* pos_w1   = (const float*)d_in[5];
  const float* pos_b1   = (const float*)d_in[6];
  const float* pos_bn_g = (const float*)d_in[7];
  const float* pos_bn_b = (const float*)d_in[8];
  const float* pos_bn_m = (const float*)d_in[9];
  const float* pos_bn_v = (const float*)d_in[10];
  const float* pos_w2   = (const float*)d_in[11];
  const float* pos_b2   = (const float*)d_in[12];
  const float* attn_w1  = (const float*)d_in[13];
  const float* attn_b1  = (const float*)d_in[14];
  const float* attn_bn_g = (const float*)d_in[15];
  const float* attn_bn_b = (const float*)d_in[16];
  const float* attn_bn_m = (const float*)d_in[17];
  const float* attn_bn_v = (const float*)d_in[18];
  const float* attn_w2  = (const float*)d_in[19];
  const float* attn_b2  = (const float*)d_in[20];
  float* out = (float*)d_out;

  short* qkvb = (short*)d_ws;                          // [NPTS*384] bf16
  short* w1p  = qkvb + (size_t)NPTS * 3 * DIM;
  short* w2p  = w1p + 65536;
  short* pw2p = w2p + 65536;
  short* wfp  = pw2p + 8192;
  short* wop  = wfp + 49152;
  float* biasq = (float*)(wop + 16384);
  float* t1sc = biasq + 384;
  float* t1bi = t1sc + 512;
  float* phsc = t1bi + 512;
  float* phbi = phsc + 64;
  float* pos_t = phbi + 64;                            // [NB*3*NN]
  int*   idx  = (int*)(pos_t + (size_t)NB * 3 * NN);   // [NPTS*16]

  pack_weights<<<998, 256, 0, stream>>>(attn_w1, attn_w2, pos_w2, w_in, w_qkv,
      w_out, pos,
      attn_b1, attn_bn_g, attn_bn_b, attn_bn_m, attn_bn_v,
      pos_b1, pos_bn_g, pos_bn_b, pos_bn_m, pos_bn_v, pos_b2,
      w1p, w2p, pw2p, wfp, wop, biasq, t1sc, t1bi, phsc, phbi, pos_t);
  knn_gemm_in<<<4352, 256, 0, stream>>>(ori_x, wfp, biasq, qkvb, pos_t, idx);
  fused_attn<<<NPTS / 4, 256, 0, stream>>>(pos_t, qkvb, idx, pos_w1,
      w1p, w2p, pw2p, wop, t1sc, t1bi, phsc, phbi, attn_b2, ori_x, out);
}

// Round 11
// 361.934 us; speedup vs baseline: 1.0217x; 1.0114x over previous
//
#include <hip/hip_runtime.h>

#define EPS 1e-5f

constexpr int NB   = 8;
constexpr int NN   = 2048;
constexpr int DIM  = 128;
constexpr int KNN  = 16;
constexpr int AH   = 512;
constexpr int NPTS = NB * NN;
constexpr float SCALE = 0.08838834764831845f; // 1/sqrt(128)

typedef __attribute__((ext_vector_type(8))) short short8;
typedef __attribute__((ext_vector_type(4))) float floatx4;

// round-half-up bf16 conversion: 2 VALU ops.
__device__ __forceinline__ short f2bf(float f) {
  union { float f; unsigned u; } a; a.f = f;
  return (short)((a.u + 0x8000u) >> 16);
}
__device__ __forceinline__ float bf2f(short s) {
  union { unsigned u; float f; } a; a.u = ((unsigned)(unsigned short)s) << 16;
  return a.f;
}

// ---------------------------------------------------------------------------
// Pack weights into bf16 B-fragment layouts + folded BN + biases + pos SoA.
// All plain-repack branches are LINEAR-READ (coalesced) / scatter-WRITE
// (fire-and-forget). Wf = w_in @ w_qkv inline dot.
// Fragment layout: frag f at [f*512 + (q*16+cc)*8 + j], value = W[k][n],
// k = ks*32 + q*8 + j.
// ---------------------------------------------------------------------------
__global__ __launch_bounds__(256) void pack_weights(
    const float* __restrict__ attn_w1, const float* __restrict__ attn_w2,
    const float* __restrict__ pos_w2, const float* __restrict__ w_in,
    const float* __restrict__ w_qkv,
    const float* __restrict__ w_out, const float* __restrict__ pos,
    const float* __restrict__ attn_b1, const float* __restrict__ abn_g,
    const float* __restrict__ abn_b, const float* __restrict__ abn_m,
    const float* __restrict__ abn_v,
    const float* __restrict__ pos_b1, const float* __restrict__ pbn_g,
    const float* __restrict__ pbn_b, const float* __restrict__ pbn_m,
    const float* __restrict__ pbn_v, const float* __restrict__ pos_b2,
    short* __restrict__ w1p, short* __restrict__ w2p, short* __restrict__ pw2p,
    short* __restrict__ wfp, short* __restrict__ wop,
    float* __restrict__ biasq,
    float* __restrict__ t1sc, float* __restrict__ t1bi,
    float* __restrict__ phsc, float* __restrict__ phbi,
    float* __restrict__ pos_t)
{
  int t = blockIdx.x * 256 + threadIdx.x;
  if (t < 65536) {                       // w1p <- attn_w1[128][512], linear read
    int k = t >> 9, n = t & 511;
    int ks = k >> 5, q = (k >> 3) & 3, j = k & 7;
    int ch = n >> 6, nt = (n >> 4) & 3, cc = n & 15;
    int dst = ch * 8192 + nt * 2048 + ks * 512 + (q * 16 + cc) * 8 + j;
    w1p[dst] = f2bf(attn_w1[t]);
  } else if (t < 131072) {               // w2p <- attn_w2[512][128], linear read
    int s = t - 65536;
    int k = s >> 7, n = s & 127;
    int ch = k >> 6, r = k & 63;
    int ks = r >> 5, q = (r >> 3) & 3, j = r & 7;
    int nt = n >> 4, cc = n & 15;
    int dst = ch * 8192 + nt * 1024 + ks * 512 + (q * 16 + cc) * 8 + j;
    w2p[dst] = f2bf(attn_w2[s]);
  } else if (t < 139264) {               // pw2p <- pos_w2[64][128], linear read
    int s = t - 131072;
    int k = s >> 7, n = s & 127;
    int ks = k >> 5, r = k & 31, q = r >> 3, j = r & 7;
    int nt = n >> 4, cc = n & 15;
    int dst = nt * 1024 + ks * 512 + (q * 16 + cc) * 8 + j;
    pw2p[dst] = f2bf(pos_w2[s]);
  } else if (t < 188416) {               // wfp: Wf=w_in@w_qkv [128x384], inline dot
    int e = t - 139264;
    int j = e & 7, lane = (e >> 3) & 63, ks = (e >> 9) & 3, nt = (e >> 11) & 7, nc = e >> 14;
    int q = lane >> 4, cc = lane & 15;
    int k = ks * 32 + q * 8 + j, n = nc * 128 + nt * 16 + cc;
    float s = 0.0f;
#pragma unroll 8
    for (int m = 0; m < 128; ++m)
      s += w_in[(size_t)k * DIM + m] * w_qkv[(size_t)m * 384 + n];
    wfp[e] = f2bf(s);
  } else if (t < 204800) {               // wop <- w_out[128][128], linear read
    int s = t - 188416;
    int k = s >> 7, n = s & 127;
    int ks = k >> 5, q = (k >> 3) & 3, j = k & 7;
    int nt = n >> 4, cc = n & 15;
    int dst = nt * 2048 + ks * 512 + (q * 16 + cc) * 8 + j;
    wop[dst] = f2bf(w_out[s]);
  } else if (t < 205184) {               // biasq[384]: pos_b2 into q,v cols
    int c = t - 204800;
    biasq[c] = (c < 128) ? pos_b2[c] : ((c < 256) ? 0.0f : pos_b2[c - 256]);
  } else if (t < 205696) {
    int c = t - 205184;
    t1sc[c] = abn_g[c] * rsqrtf(abn_v[c] + EPS);
  } else if (t < 206208) {
    int c = t - 205696;
    float sc = abn_g[c] * rsqrtf(abn_v[c] + EPS);
    t1bi[c] = (attn_b1[c] - abn_m[c]) * sc + abn_b[c];
  } else if (t < 206272) {
    int c = t - 206208;
    phsc[c] = pbn_g[c] * rsqrtf(pbn_v[c] + EPS);
  } else if (t < 206336) {
    int c = t - 206272;
    float sc = pbn_g[c] * rsqrtf(pbn_v[c] + EPS);
    phbi[c] = (pos_b1[c] - pbn_m[c]) * sc + pbn_b[c];
  } else if (t < 206336 + NPTS * 3) {    // pos -> SoA pos_t[b][3][NN]
    int e = t - 206336;
    int p = e / 3, d = e - p * 3;
    int b = p >> 11, n = p & (NN - 1);
    pos_t[((size_t)b * 3 + d) * NN + n] = pos[e];
  }
}

// ---------------------------------------------------------------------------
// Grid-fused: gemm_in (256 tile-blocks) + KNN (2048 blocks, 2 points/wave
// for ILP: two independent argmin chains per wave + shared candidate loads).
// bx%9==0 -> gemm tile; else knn octet.
// ---------------------------------------------------------------------------
__global__ __launch_bounds__(256, 4) void knn_gemm_in(
    const float* __restrict__ A, const short* __restrict__ wfp,
    const float* __restrict__ biasq, short* __restrict__ C,
    const float* __restrict__ pos_t, int* __restrict__ idx_out)
{
  __shared__ short As[64 * 128];
  const int tid = threadIdx.x;
  const int bx = blockIdx.x;

  if (bx % 9 == 0) {
    // ---- gemm_in tile: qkv[64x384] = bf16(ori_x tile) @ wfp + biasq ----
    const int lane = tid & 63, w = tid >> 6;
    const int wr = w >> 1, wc = w & 1;
    const int q = lane >> 4, cc = lane & 15;
    const int row0 = (bx / 9) * 64;
#pragma unroll
    for (int it = 0; it < 4; ++it) {
      int e = tid + it * 256;
      int row = e >> 4, cg = e & 15;
      const float* src = A + (size_t)(row0 + row) * 128 + cg * 8;
      float4 f0 = *(const float4*)src, f1 = *(const float4*)(src + 4);
      short8 v;
      v[0] = f2bf(f0.x); v[1] = f2bf(f0.y); v[2] = f2bf(f0.z); v[3] = f2bf(f0.w);
      v[4] = f2bf(f1.x); v[5] = f2bf(f1.y); v[6] = f2bf(f1.z); v[7] = f2bf(f1.w);
      *(short8*)(As + row * 128 + ((cg ^ (row & 15)) << 3)) = v;
    }
    __syncthreads();
    for (int nc = 0; nc < 3; ++nc) {
      floatx4 acc[2][4];
#pragma unroll
      for (int i = 0; i < 2; ++i)
#pragma unroll
        for (int jt = 0; jt < 4; ++jt) acc[i][jt] = (floatx4){0.f, 0.f, 0.f, 0.f};
#pragma unroll
      for (int ks = 0; ks < 4; ++ks) {
        short8 a8[2], b8[4];
#pragma unroll
        for (int i = 0; i < 2; ++i) {
          int row = (wr * 2 + i) * 16 + cc;
          a8[i] = *(const short8*)(As + row * 128 + (((ks * 4 + q) ^ cc) << 3));
        }
#pragma unroll
        for (int jt = 0; jt < 4; ++jt)
          b8[jt] = *(const short8*)(wfp + ((((nc * 8 + wc * 4 + jt) * 4 + ks) * 64 + lane) << 3));
#pragma unroll
        for (int i = 0; i < 2; ++i)
#pragma unroll
          for (int jt = 0; jt < 4; ++jt)
            acc[i][jt] = __builtin_amdgcn_mfma_f32_16x16x32_bf16(a8[i], b8[jt], acc[i][jt], 0, 0, 0);
      }
#pragma unroll
      for (int jt = 0; jt < 4; ++jt) {
        int colG = nc * 128 + (wc * 4 + jt) * 16 + cc;
        float bv = biasq[colG];
#pragma unroll
        for (int i = 0; i < 2; ++i)
#pragma unroll
          for (int r = 0; r < 4; ++r) {
            int row = (wr * 2 + i) * 16 + q * 4 + r;
            C[(size_t)(row0 + row) * 384 + colG] = f2bf(acc[i][jt][r] + bv);
          }
      }
    }
  } else {
    // ---- KNN: 8 points/block, 2 per wave (interleaved chains) ----
    const int kb = bx - bx / 9 - 1;          // 0..2047
    const int lane = tid & 63;
    const int p0 = kb * 8 + (tid >> 6) * 2;  // points p0, p0+1 (same batch)
    const int b = p0 >> 11, i0 = p0 & (NN - 1), i1 = i0 + 1;
    const float* px = pos_t + (size_t)b * 3 * NN;
    const float* py = px + NN;
    const float* pz = py + NN;
    const float xa = px[i0], ya = py[i0], za = pz[i0];
    const float sqa = xa * xa + ya * ya + za * za;
    const float xb = px[i1], yb = py[i1], zb = pz[i1];
    const float sqb = xb * xb + yb * yb + zb * zb;
    float va[32], vb[32];
#pragma unroll
    for (int t = 0; t < 32; ++t) {
      int j = t * 64 + lane;
      float xj = px[j], yj = py[j], zj = pz[j];
      float sqj = xj * xj + yj * yj + zj * zj;
      va[t] = sqa + sqj - 2.0f * (xa * xj + ya * yj + za * zj);
      vb[t] = sqb + sqj - 2.0f * (xb * xj + yb * yj + zb * zj);
    }
    for (int s = 0; s < KNN; ++s) {
      float av = 3.4e38f; int aj = 1 << 30;
      float bv = 3.4e38f; int bj = 1 << 30;
#pragma unroll
      for (int t = 0; t < 32; ++t) {
        if (va[t] < av) { av = va[t]; aj = t * 64 + lane; }
        if (vb[t] < bv) { bv = vb[t]; bj = t * 64 + lane; }
      }
#pragma unroll
      for (int m = 1; m < 64; m <<= 1) {
        float oav = __shfl_xor(av, m); int oaj = __shfl_xor(aj, m);
        float obv = __shfl_xor(bv, m); int obj = __shfl_xor(bj, m);
        if (oav < av || (oav == av && oaj < aj)) { av = oav; aj = oaj; }
        if (obv < bv || (obv == bv && obj < bj)) { bv = obv; bj = obj; }
      }
      if (lane == 0) {
        idx_out[(size_t)p0 * KNN + s] = aj;
        idx_out[(size_t)(p0 + 1) * KNN + s] = bj;
      }
#pragma unroll
      for (int t = 0; t < 32; ++t) {
        if (aj == t * 64 + lane) va[t] = 3.4e38f;
        if (bj == t * 64 + lane) vb[t] = 3.4e38f;
      }
    }
  }
}

// ---------------------------------------------------------------------------
// Fused MFMA attention + out-projection: 4 points/block (M=64), 4 waves each
// 32x64, 64-col AH chunks, dbuf t1, vpe in LDS. Cooperative vectorized k/v
// gather through LDS (16B loads) + in-place combine. Out-proj agg tile at
// pitch 136 (bank-conflict-free). LDS ~50 KB -> 3 blocks/CU.
// ---------------------------------------------------------------------------
__global__ __launch_bounds__(256, 3) void fused_attn(
    const float* __restrict__ pos_t, const short* __restrict__ qkv,
    const int* __restrict__ knn_idx,
    const float* __restrict__ pos_w1,
    const short* __restrict__ w1p, const short* __restrict__ w2p,
    const short* __restrict__ pw2p, const short* __restrict__ wop,
    const float* __restrict__ t1sc, const float* __restrict__ t1bi,
    const float* __restrict__ phsc, const float* __restrict__ phbi,
    const float* __restrict__ attn_b2,
    const float* __restrict__ ori_x, float* __restrict__ out)
{
  __shared__ short a_s[64 * 128];       // 16 KB, XOR swizzle on row&15
  __shared__ short vpe_s[64 * 128];     // 16 KB, same swizzle
  __shared__ short t1_s[2][64 * 64];    // 16 KB, XOR swizzle on row&7
  __shared__ short q_ss[4 * 128];       // 1 KB bf16 q rows
  __shared__ float relp_s[64 * 4];
  __shared__ int   nbr_s[64];

  const int tid = threadIdx.x;
  const int lane = tid & 63, w = tid >> 6;
  const int wr = w >> 1, wc = w & 1;
  const int q = lane >> 4, cc = lane & 15;
  const int bb = blockIdx.x & 7;                     // XCD-affinity swizzle
  const int base = (blockIdx.x >> 3) * 4;
  const int gp0 = bb * NN + base;

  const float* px = pos_t + (size_t)bb * 3 * NN;
  const float* py = px + NN;
  const float* pz = py + NN;

  if (tid < 64) nbr_s[tid] = knn_idx[(size_t)gp0 * KNN + tid];
  else if (tid < 128) {                 // stage q rows (bf16)
    int e = tid - 64;
    int p = e >> 4, seg = e & 15;
    *(short8*)(q_ss + p * 128 + seg * 8) =
        *(const short8*)(qkv + (size_t)(gp0 + p) * 384 + seg * 8);
  }
  __syncthreads();
  if (tid < 64) {
    int p = tid >> 4;
    int j = nbr_s[tid];
    relp_s[tid * 4 + 0] = px[base + p] - px[j];
    relp_s[tid * 4 + 1] = py[base + p] - py[j];
    relp_s[tid * 4 + 2] = pz[base + p] - pz[j];
  }
  __syncthreads();

  // ph = relu(bn(relp @ pos_w1 + b1)) -> t1_s[0] (64 rows x 64 cols)
#pragma unroll
  for (int r2 = 0; r2 < 16; ++r2) {
    int e = tid + r2 * 256;
    int row = e >> 6, c = e & 63;
    float lin = relp_s[row * 4] * pos_w1[c] + relp_s[row * 4 + 1] * pos_w1[64 + c]
              + relp_s[row * 4 + 2] * pos_w1[128 + c];
    t1_s[0][row * 64 + (((c >> 3) ^ (row & 7)) << 3) + (c & 7)] =
        f2bf(fmaxf(lin * phsc[c] + phbi[c], 0.0f));
  }
  __syncthreads();

  // pe = ph @ pos_w2 (pos_b2 pre-folded into qkv q/v cols)
  floatx4 pe[2][4];
#pragma unroll
  for (int i = 0; i < 2; ++i)
#pragma unroll
    for (int jt = 0; jt < 4; ++jt) pe[i][jt] = (floatx4){0.f, 0.f, 0.f, 0.f};
#pragma unroll
  for (int ks = 0; ks < 2; ++ks) {
    short8 a8[2];
#pragma unroll
    for (int i = 0; i < 2; ++i) {
      int row = (wr * 2 + i) * 16 + cc;
      a8[i] = *(const short8*)(t1_s[0] + row * 64 + (((ks * 4 + q) ^ (row & 7)) << 3));
    }
#pragma unroll
    for (int jt = 0; jt < 4; ++jt) {
      short8 b8 = *(const short8*)(pw2p + ((((wc * 4 + jt) * 2 + ks) * 64 + lane) << 3));
#pragma unroll
      for (int i = 0; i < 2; ++i)
        pe[i][jt] = __builtin_amdgcn_mfma_f32_16x16x32_bf16(a8[i], b8, pe[i][jt], 0, 0, 0);
    }
  }

  // cooperative vectorized gather: k rows -> a_s slots, v rows -> vpe_s slots
  // (16B coalesced loads; slot layout matches the XOR swizzle exactly)
#pragma unroll
  for (int it = 0; it < 4; ++it) {
    int e = tid + it * 256;             // 1024 tasks: row = e>>4, group = e&15
    int row = e >> 4, g = e & 15;
    const short* kvrow = qkv + ((size_t)bb * NN + nbr_s[row]) * 384;
    int dst = row * 128 + ((g ^ (row & 15)) << 3);
    *(short8*)(a_s + dst)   = *(const short8*)(kvrow + 128 + g * 8);
    *(short8*)(vpe_s + dst) = *(const short8*)(kvrow + 256 + g * 8);
  }
  __syncthreads();   // gather visible; pe reads of t1_s[0] complete

  // in-place combine: a = q - k + pe ; vpe = v + pe
#pragma unroll
  for (int i = 0; i < 2; ++i) {
    int rt = wr * 2 + i;
#pragma unroll
    for (int jt = 0; jt < 4; ++jt) {
      int col = (wc * 4 + jt) * 16 + cc;
      float qv = bf2f(q_ss[rt * 128 + col]);
#pragma unroll
      for (int r = 0; r < 4; ++r) {
        int row = rt * 16 + q * 4 + r;
        float pev = pe[i][jt][r];
        int slot = row * 128 + (((col >> 3) ^ (row & 15)) << 3) + (col & 7);
        a_s[slot]   = f2bf(qv - bf2f(a_s[slot]) + pev);
        vpe_s[slot] = f2bf(bf2f(vpe_s[slot]) + pev);
      }
    }
  }
  __syncthreads();   // a_s/vpe_s fully built

  floatx4 hacc[2][4];
#pragma unroll
  for (int i = 0; i < 2; ++i)
#pragma unroll
    for (int jt = 0; jt < 4; ++jt) hacc[i][jt] = (floatx4){0.f, 0.f, 0.f, 0.f};

  for (int ch = 0; ch < 8; ++ch) {
    short* t1b = t1_s[ch & 1];
    // GEMM1: tacc = a @ w1[:, ch*64 : +64]
    floatx4 tacc[2][2];
#pragma unroll
    for (int i = 0; i < 2; ++i)
#pragma unroll
      for (int jt = 0; jt < 2; ++jt) tacc[i][jt] = (floatx4){0.f, 0.f, 0.f, 0.f};
#pragma unroll
    for (int ks = 0; ks < 4; ++ks) {
      short8 a8[2], b8[2];
#pragma unroll
      for (int i = 0; i < 2; ++i) {
        int row = (wr * 2 + i) * 16 + cc;
        a8[i] = *(const short8*)(a_s + row * 128 + (((ks * 4 + q) ^ cc) << 3));
      }
#pragma unroll
      for (int jt = 0; jt < 2; ++jt)
        b8[jt] = *(const short8*)(w1p + ((((ch * 4 + wc * 2 + jt) * 4 + ks) * 64 + lane) << 3));
#pragma unroll
      for (int i = 0; i < 2; ++i)
#pragma unroll
        for (int jt = 0; jt < 2; ++jt)
          tacc[i][jt] = __builtin_amdgcn_mfma_f32_16x16x32_bf16(a8[i], b8[jt], tacc[i][jt], 0, 0, 0);
    }
    // bn/relu -> t1b (64-col, swizzled)
#pragma unroll
    for (int jt = 0; jt < 2; ++jt) {
      int colL = (wc * 2 + jt) * 16 + cc;
      int colG = ch * 64 + colL;
      float sc = t1sc[colG], bi = t1bi[colG];
#pragma unroll
      for (int i = 0; i < 2; ++i)
#pragma unroll
        for (int r = 0; r < 4; ++r) {
          int row = (wr * 2 + i) * 16 + q * 4 + r;
          t1b[row * 64 + (((colL >> 3) ^ (row & 7)) << 3) + (colL & 7)] =
              f2bf(fmaxf(tacc[i][jt][r] * sc + bi, 0.0f));
        }
    }
    __syncthreads();   // t1b visible; ping-pong protects in-flight reads
    // GEMM2: hacc += t1 @ w2[ch*64 : +64, :]
#pragma unroll
    for (int ks = 0; ks < 2; ++ks) {
      short8 a8[2], b8[4];
#pragma unroll
      for (int i = 0; i < 2; ++i) {
        int row = (wr * 2 + i) * 16 + cc;
        a8[i] = *(const short8*)(t1b + row * 64 + (((ks * 4 + q) ^ (row & 7)) << 3));
      }
#pragma unroll
      for (int jt = 0; jt < 4; ++jt)
        b8[jt] = *(const short8*)(w2p + ((((ch * 8 + wc * 4 + jt) * 2 + ks) * 64 + lane) << 3));
#pragma unroll
      for (int i = 0; i < 2; ++i)
#pragma unroll
        for (int jt = 0; jt < 4; ++jt)
          hacc[i][jt] = __builtin_amdgcn_mfma_f32_16x16x32_bf16(a8[i], b8[jt], hacc[i][jt], 0, 0, 0);
    }
  }

  // softmax over 16 neighbors per (point, channel); agg -> agg_s (pitch 136)
  short* agg_s = t1_s[0];   // 16 rows x pitch 136 bf16 (rows 0..3 = points)
#pragma unroll
  for (int i = 0; i < 2; ++i) {
    int rt = wr * 2 + i;
#pragma unroll
    for (int jt = 0; jt < 4; ++jt) {
      int col = (wc * 4 + jt) * 16 + cc;
      float b2v = attn_b2[col];
      float v0[4], mx = -3.4e38f;
#pragma unroll
      for (int r = 0; r < 4; ++r) {
        v0[r] = (hacc[i][jt][r] + b2v) * SCALE;
        mx = fmaxf(mx, v0[r]);
      }
      mx = fmaxf(mx, __shfl_xor(mx, 16));
      mx = fmaxf(mx, __shfl_xor(mx, 32));
      float ex[4], sum = 0.f;
#pragma unroll
      for (int r = 0; r < 4; ++r) { ex[r] = __expf(v0[r] - mx); sum += ex[r]; }
      sum += __shfl_xor(sum, 16);
      sum += __shfl_xor(sum, 32);
      float inv = 1.0f / sum;
      float part = 0.f;
#pragma unroll
      for (int r = 0; r < 4; ++r) {
        int row = rt * 16 + q * 4 + r;
        int slot = row * 128 + (((col >> 3) ^ (row & 15)) << 3) + (col & 7);
        part += ex[r] * bf2f(vpe_s[slot]);
      }
      part += __shfl_xor(part, 16);
      part += __shfl_xor(part, 32);
      if (q == 0) agg_s[rt * 136 + col] = f2bf(part * inv);
    }
  }
  __syncthreads();

  // out-projection: out[4x128] = agg @ w_out + ori_x. Rows 4..15 of the A
  // tile are stale garbage — harmless, C rows 4..15 are never stored.
  {
    floatx4 oacc[2];
#pragma unroll
    for (int jt = 0; jt < 2; ++jt) oacc[jt] = (floatx4){0.f, 0.f, 0.f, 0.f};
#pragma unroll
    for (int ks = 0; ks < 4; ++ks) {
      short8 a8 = *(const short8*)(agg_s + cc * 136 + ks * 32 + q * 8);
#pragma unroll
      for (int jt = 0; jt < 2; ++jt) {
        short8 b8 = *(const short8*)(wop + ((((w * 2 + jt) * 4 + ks) * 64 + lane) << 3));
        oacc[jt] = __builtin_amdgcn_mfma_f32_16x16x32_bf16(a8, b8, oacc[jt], 0, 0, 0);
      }
    }
    if (q == 0) {
#pragma unroll
      for (int jt = 0; jt < 2; ++jt) {
        int col = (w * 2 + jt) * 16 + cc;
#pragma unroll
        for (int r = 0; r < 4; ++r) {
          size_t o = (size_t)(gp0 + r) * 128 + col;
          out[o] = oacc[jt][r] + ori_x[o];
        }
      }
    }
  }
}

extern "C" void kernel_launch(void* const* d_in, const int* in_sizes, int n_in,
                              void* d_out, int out_size, void* d_ws, size_t ws_size,
                              hipStream_t stream)
{
  const float* ori_x    = (const float*)d_in[0];
  const float* pos      = (const float*)d_in[1];
  const float* w_in     = (const float*)d_in[2];
  const float* w_qkv    = (const float*)d_in[3];
  const float* w_out    = (const float*)d_in[4];
  const float* pos_w1   = (const float*)d_in[5];
  const float* pos_b1   = (const float*)d_in[6];
  const float* pos_bn_g = (const float*)d_in[7];
  const float* pos_bn_b = (const float*)d_in[8];
  const float* pos_bn_m = (const float*)d_in[9];
  const float* pos_bn_v = (const float*)d_in[10];
  const float* pos_w2   = (const float*)d_in[11];
  const float* pos_b2   = (const float*)d_in[12];
  const float* attn_w1  = (const float*)d_in[13];
  const float* attn_b1  = (const float*)d_in[14];
  const float* attn_bn_g = (const float*)d_in[15];
  const float* attn_bn_b = (const float*)d_in[16];
  const float* attn_bn_m = (const float*)d_in[17];
  const float* attn_bn_v = (const float*)d_in[18];
  const float* attn_w2  = (const float*)d_in[19];
  const float* attn_b2  = (const float*)d_in[20];
  float* out = (float*)d_out;

  short* qkvb = (short*)d_ws;                          // [NPTS*384] bf16
  short* w1p  = qkvb + (size_t)NPTS * 3 * DIM;
  short* w2p  = w1p + 65536;
  short* pw2p = w2p + 65536;
  short* wfp  = pw2p + 8192;
  short* wop  = wfp + 49152;
  float* biasq = (float*)(wop + 16384);
  float* t1sc = biasq + 384;
  float* t1bi = t1sc + 512;
  float* phsc = t1bi + 512;
  float* phbi = phsc + 64;
  float* pos_t = phbi + 64;                            // [NB*3*NN]
  int*   idx  = (int*)(pos_t + (size_t)NB * 3 * NN);   // [NPTS*16]

  pack_weights<<<998, 256, 0, stream>>>(attn_w1, attn_w2, pos_w2, w_in, w_qkv,
      w_out, pos,
      attn_b1, attn_bn_g, attn_bn_b, attn_bn_m, attn_bn_v,
      pos_b1, pos_bn_g, pos_bn_b, pos_bn_m, pos_bn_v, pos_b2,
      w1p, w2p, pw2p, wfp, wop, biasq, t1sc, t1bi, phsc, phbi, pos_t);
  knn_gemm_in<<<2304, 256, 0, stream>>>(ori_x, wfp, biasq, qkvb, pos_t, idx);
  fused_attn<<<NPTS / 4, 256, 0, stream>>>(pos_t, qkvb, idx, pos_w1,
      w1p, w2p, pw2p, wop, t1sc, t1bi, phsc, phbi, attn_b2, ori_x, out);
}